// Round 4
// baseline (236.803 us; speedup 1.0000x reference)
//
#include <hip/hip_runtime.h>

#define D256 256
#define TOTROWS 65536          // B*A*I = 4*32*512
#define BM 32                  // rows per tile
#define LDW 264                // padded LDS row stride in u16 (528 B): 0 conflicts
#define TPB 4                  // tiles per block (persistent, double-buffered)
#define NBLKS (TOTROWS / (BM * TPB))   // 512 = 2 blocks/CU
#define NT 512                 // 8 waves; wave wv owns 32-col panel wv

typedef unsigned short u16;
typedef unsigned int u32;
typedef __attribute__((ext_vector_type(8))) short bf16x8;
typedef __attribute__((ext_vector_type(16))) float f32x16;

__device__ __forceinline__ float b2f(u16 u) {
  union { u32 i; float f; } v; v.i = ((u32)u) << 16; return v.f;
}
__device__ __forceinline__ u16 f2b(float f) {
  union { float f; u32 i; } v; v.f = f;
  return (u16)((v.i + 0x7fffu + ((v.i >> 16) & 1u)) >> 16);  // RNE
}
// packed RNE f32x2 -> bf16x2 (single VALU instr; bit-identical to f2b)
__device__ __forceinline__ u32 f2b2(float lo, float hi) {
  u32 r;
  asm("v_cvt_pk_bf16_f32 %0, %1, %2" : "=v"(r) : "v"(lo), "v"(hi));
  return r;
}

// Build weight fragments in MFMA B-operand lane order, bf16 (verified r0-r2):
//   Wf[m][p][k][ln] (16B chunk) = Brow[m][col = p*32 + (ln&31)][k*16 + (ln>>5)*8 ..+8]
// Brow[0]=attn1, Brow[1]=attn2 (row-major [n][k]); Brow[2][n][j]=W1[j][n]; Brow[3][n][j]=W2[j][n].
__global__ void build_wfrag(const float* __restrict__ a1,
                            const float* __restrict__ a2,
                            const float* __restrict__ W1,
                            const float* __restrict__ W2,
                            u16* __restrict__ Wf) {
  const int m = blockIdx.y;
  const int idx = blockIdx.x * 256 + threadIdx.x;   // 0..8191 per matrix
  int col, c;
  const float* src;
  if (m < 2) { col = idx >> 5; c = idx & 31; src = m ? a2 : a1; }
  else       { col = idx & 255; c = idx >> 8; src = (m == 3) ? W2 : W1; }
  const int kk0 = c * 8;
  const int p = col >> 5, l31 = col & 31, lhh = c & 1, k = c >> 1;
  const int ln = lhh * 32 + l31;
  u16* dst = Wf + m * 65536 + ((p * 16 + k) * 64 + ln) * 8;
  u16 v[8];
  if (m < 2) {
#pragma unroll
    for (int j = 0; j < 8; j++) v[j] = f2b(src[col * 256 + kk0 + j]);
  } else {
#pragma unroll
    for (int j = 0; j < 8; j++) v[j] = f2b(src[(kk0 + j) * 256 + col]);
  }
  ushort4 lo, hi;
  lo.x = v[0]; lo.y = v[1]; lo.z = v[2]; lo.w = v[3];
  hi.x = v[4]; hi.y = v[5]; hi.z = v[6]; hi.w = v[7];
  ((ushort4*)dst)[0] = lo;
  ((ushort4*)dst)[1] = hi;
}

// split-reduce: v[16] per-lane partials (rows (r&3)+8*(r>>2)+4*lh, col = base+l31)
// -> 32-lane column sums accumulated into sp[row] (row 0..31). 31 shfls. (verified)
__device__ __forceinline__ void reduce_accum(float v[16], float* sp,
                                             int l31, int lh) {
#pragma unroll
  for (int r = 0; r < 8; r++) {
    float a = v[r]     + __shfl_xor(v[r],     1, 32);
    float b = v[r + 8] + __shfl_xor(v[r + 8], 1, 32);
    v[r] = (l31 & 1) ? b : a;
  }
#pragma unroll
  for (int r = 0; r < 4; r++) {
    float a = v[r]     + __shfl_xor(v[r],     2, 32);
    float b = v[r + 4] + __shfl_xor(v[r + 4], 2, 32);
    v[r] = (l31 & 2) ? b : a;
  }
#pragma unroll
  for (int r = 0; r < 2; r++) {
    float a = v[r]     + __shfl_xor(v[r],     4, 32);
    float b = v[r + 2] + __shfl_xor(v[r + 2], 4, 32);
    v[r] = (l31 & 4) ? b : a;
  }
  {
    float a = v[0] + __shfl_xor(v[0], 8, 32);
    float b = v[1] + __shfl_xor(v[1], 8, 32);
    v[0] = (l31 & 8) ? b : a;
  }
  v[0] += __shfl_xor(v[0], 16, 32);
  if (l31 < 16) {
    const int i = ((l31 & 1) << 3) | ((l31 & 2) << 1) | ((l31 & 4) >> 1) |
                  ((l31 & 8) >> 3);
    const int row = (i & 3) + 8 * (i >> 2) + 4 * lh;
    atomicAdd(&sp[row], v[0]);
  }
}

__global__ __launch_bounds__(NT, 2)
void fused(const float* __restrict__ X0g, const float* __restrict__ X1g,
           const u16* __restrict__ Wf, float* __restrict__ outg) {
  __shared__ u16 lX0[2][BM][LDW];   // 2 x 16.9 KB
  __shared__ u16 lX1[2][BM][LDW];   // 2 x 16.9 KB -> 68.1 KB total, 2 blocks/CU
  __shared__ float sp0[BM], sp1[BM], sc0[BM], sc1[BM];

  const int t   = threadIdx.x;
  const int ln  = t & 63;
  const int wv  = t >> 6;      // wave 0..7 = column panel
  const int l31 = ln & 31;
  const int lh  = ln >> 5;
  const int cb  = wv * 32;

  const size_t base = (size_t)blockIdx.x * (TPB * BM);

  // fragment-ordered weight streams: 1KB contiguous per (mat, k)
  const u16* wA1 = Wf + 0 * 65536 + (wv * 16) * 512 + ln * 8;
  const u16* wA2 = Wf + 1 * 65536 + (wv * 16) * 512 + ln * 8;
  const u16* wW1 = Wf + 2 * 65536 + (wv * 16) * 512 + ln * 8;
  const u16* wW2 = Wf + 3 * 65536 + (wv * 16) * 512 + ln * 8;

  // stage helpers (verified r0/r2 index math: e = i*NT+t over 2048 float4/tensor)
  auto stage_load = [&](size_t rowbase, float4* na, float4* nb) {
    const float4* g0 = (const float4*)(X0g + rowbase * D256);
    const float4* g1 = (const float4*)(X1g + rowbase * D256);
#pragma unroll
    for (int i = 0; i < 4; i++) {
      na[i] = g0[i * NT + t];
      nb[i] = g1[i * NT + t];
    }
  };
  auto stage_write = [&](int b, const float4* na, const float4* nb) {
    uint2* s0 = (uint2*)&lX0[b][0][0];   // row stride = 66 uint2
    uint2* s1 = (uint2*)&lX1[b][0][0];
#pragma unroll
    for (int i = 0; i < 4; i++) {
      const int e = i * NT + t;
      const int row = e >> 6;
      const int col = e & 63;
      uint2 pa, pb;
      pa.x = f2b2(na[i].x, na[i].y); pa.y = f2b2(na[i].z, na[i].w);
      pb.x = f2b2(nb[i].x, nb[i].y); pb.y = f2b2(nb[i].z, nb[i].w);
      s0[row * 66 + col] = pa;
      s1[row * 66 + col] = pb;
    }
  };

  if (t < BM) sp0[t] = 0.f;
  else if (t < 2 * BM) sp1[t - BM] = 0.f;

  // prologue: stage tile 0 into buf 0
  {
    float4 pa[4], pb[4];
    stage_load(base, pa, pb);
    stage_write(0, pa, pb);
  }
  __syncthreads();

  int buf = 0;
  for (int tt = 0; tt < TPB; tt++) {
    const size_t trow = base + (size_t)tt * BM;
    const bool pf = (tt + 1 < TPB);

    // (1) issue next tile's global loads early; consumed after the epilogue.
    float4 na[4], nb[4];
    if (pf) stage_load(trow + BM, na, nb);

    // (2) pass 1: gate scores (verified r0 code on lX*[buf])
    {
      f32x16 G0, G1;
#pragma unroll
      for (int i = 0; i < 16; i++) { G0[i] = 0.f; G1[i] = 0.f; }

#pragma unroll 4
      for (int k = 0; k < 16; k++) {
        bf16x8 af0 = *(const bf16x8*)(&lX0[buf][l31][k * 16 + lh * 8]);
        bf16x8 af1 = *(const bf16x8*)(&lX1[buf][l31][k * 16 + lh * 8]);
        G0 = __builtin_amdgcn_mfma_f32_32x32x16_bf16(
            af0, *(const bf16x8*)(wA1 + k * 512), G0, 0, 0, 0);
        G1 = __builtin_amdgcn_mfma_f32_32x32x16_bf16(
            af1, *(const bf16x8*)(wA2 + k * 512), G1, 0, 0, 0);
      }

      float v[16];
#pragma unroll
      for (int r = 0; r < 16; r++) {   // gate0: Z0 = X0@A1^T, other = X1
        const int row = (r & 3) + 8 * (r >> 2) + 4 * lh;
        v[r] = G0[r] * b2f(lX1[buf][row][cb + l31]);
      }
      reduce_accum(v, sp0, l31, lh);
#pragma unroll
      for (int r = 0; r < 16; r++) {   // gate1: Z1 = X1@A2^T, other = X0
        const int row = (r & 3) + 8 * (r >> 2) + 4 * lh;
        v[r] = G1[r] * b2f(lX0[buf][row][cb + l31]);
      }
      reduce_accum(v, sp1, l31, lh);
    }
    __syncthreads();   // sp complete

    // (3) sigmoid + sp re-zero for the next tile
    if (t < BM)          { sc0[t] = 1.f + 1.f / (1.f + __expf(-sp0[t]));
                           sp0[t] = 0.f; }
    else if (t < 2 * BM) { sc1[t - BM] = 1.f + 1.f / (1.f + __expf(-sp1[t - BM]));
                           sp1[t - BM] = 0.f; }
    __syncthreads();   // sc visible

    // (4) pass 2: projections + epilogue (verified r0 code)
    {
      f32x16 P0, P1;
#pragma unroll
      for (int i = 0; i < 16; i++) { P0[i] = 0.f; P1[i] = 0.f; }

#pragma unroll 4
      for (int k = 0; k < 16; k++) {
        bf16x8 af0 = *(const bf16x8*)(&lX0[buf][l31][k * 16 + lh * 8]);
        bf16x8 af1 = *(const bf16x8*)(&lX1[buf][l31][k * 16 + lh * 8]);
        P0 = __builtin_amdgcn_mfma_f32_32x32x16_bf16(
            af0, *(const bf16x8*)(wW1 + k * 512), P0, 0, 0, 0);
        P1 = __builtin_amdgcn_mfma_f32_32x32x16_bf16(
            af1, *(const bf16x8*)(wW2 + k * 512), P1, 0, 0, 0);
      }

      float* opb = outg + trow * D256 + cb;
#pragma unroll
      for (int q = 0; q < 4; q++) {
        float s0a[4], s1a[4];
        *(float4*)s0a = *(const float4*)&sc0[8 * q + 4 * lh];
        *(float4*)s1a = *(const float4*)&sc1[8 * q + 4 * lh];
#pragma unroll
        for (int j = 0; j < 4; j++) {
          const int r = q * 4 + j;
          const int row = j + 8 * q + 4 * lh;
          __builtin_nontemporal_store(s0a[j] * P0[r] + s1a[j] * P1[r],
                                      &opb[row * D256 + l31]);
        }
      }
    }

    // (5) write-late: convert prefetched tile into the other buffer.
    // Safe: buf^1's last readers finished before the end-of-previous-iteration
    // barrier; next iteration reads it only after the barrier below.
    if (pf) stage_write(buf ^ 1, na, nb);
    __syncthreads();
    buf ^= 1;
  }
}

extern "C" void kernel_launch(void* const* d_in, const int* in_sizes, int n_in,
                              void* d_out, int out_size, void* d_ws, size_t ws_size,
                              hipStream_t stream) {
  const float* i0 = (const float*)d_in[0];
  const float* i1 = (const float*)d_in[1];
  const float* W1 = (const float*)d_in[2];
  const float* W2 = (const float*)d_in[3];
  const float* a1 = (const float*)d_in[4];
  const float* a2 = (const float*)d_in[5];
  u16* Wf = (u16*)d_ws;   // 4 x 256x256 bf16 = 512 KB, fragment-ordered

  build_wfrag<<<dim3(32, 4), 256, 0, stream>>>(a1, a2, W1, W2, Wf);
  fused<<<NBLKS, NT, 0, stream>>>(i0, i1, Wf, (float*)d_out);
}

// Round 5
// 218.609 us; speedup vs baseline: 1.0832x; 1.0832x over previous
//
#include <hip/hip_runtime.h>

#define D256 256
#define TOTROWS 65536   // B*A*I = 4*32*512
#define BM 32
#define LDW 264         // padded LDS row stride in u16 (528 B): 0 bank conflicts
#define NBLK (TOTROWS / BM)   // 2048
#define NT 512                // 8 waves; wave wv owns 32-col panel wv

typedef unsigned short u16;
typedef unsigned int u32;
typedef __attribute__((ext_vector_type(8))) short bf16x8;
typedef __attribute__((ext_vector_type(16))) float f32x16;

__device__ __forceinline__ float b2f(u16 u) {
  union { u32 i; float f; } v; v.i = ((u32)u) << 16; return v.f;
}
__device__ __forceinline__ u16 f2b(float f) {
  union { float f; u32 i; } v; v.f = f;
  return (u16)((v.i + 0x7fffu + ((v.i >> 16) & 1u)) >> 16);  // RNE
}
// packed RNE f32x2 -> bf16x2 (single VALU instr; bit-identical to f2b)
__device__ __forceinline__ u32 f2b2(float lo, float hi) {
  u32 r;
  asm("v_cvt_pk_bf16_f32 %0, %1, %2" : "=v"(r) : "v"(lo), "v"(hi));
  return r;
}

// Build weight fragments in MFMA B-operand lane order, bf16 (verified r0-r2,r4):
//   Wf[m][p][k][ln] (16B chunk) = Brow[m][col = p*32 + (ln&31)][k*16 + (ln>>5)*8 ..+8]
// Brow[0]=attn1, Brow[1]=attn2 (row-major [n][k]); Brow[2][n][j]=W1[j][n]; Brow[3][n][j]=W2[j][n].
__global__ void build_wfrag(const float* __restrict__ a1,
                            const float* __restrict__ a2,
                            const float* __restrict__ W1,
                            const float* __restrict__ W2,
                            u16* __restrict__ Wf) {
  const int m = blockIdx.y;
  const int idx = blockIdx.x * 256 + threadIdx.x;   // 0..8191 per matrix
  int col, c;
  const float* src;
  if (m < 2) { col = idx >> 5; c = idx & 31; src = m ? a2 : a1; }
  else       { col = idx & 255; c = idx >> 8; src = (m == 3) ? W2 : W1; }
  const int kk0 = c * 8;
  const int p = col >> 5, l31 = col & 31, lhh = c & 1, k = c >> 1;
  const int ln = lhh * 32 + l31;
  u16* dst = Wf + m * 65536 + ((p * 16 + k) * 64 + ln) * 8;
  u16 v[8];
  if (m < 2) {
#pragma unroll
    for (int j = 0; j < 8; j++) v[j] = f2b(src[col * 256 + kk0 + j]);
  } else {
#pragma unroll
    for (int j = 0; j < 8; j++) v[j] = f2b(src[(kk0 + j) * 256 + col]);
  }
  ushort4 lo, hi;
  lo.x = v[0]; lo.y = v[1]; lo.z = v[2]; lo.w = v[3];
  hi.x = v[4]; hi.y = v[5]; hi.z = v[6]; hi.w = v[7];
  ((ushort4*)dst)[0] = lo;
  ((ushort4*)dst)[1] = hi;
}

// split-reduce: v[16] per-lane partials (rows (r&3)+8*(r>>2)+4*lh, col = base+l31)
// -> 32-lane column sums accumulated into sp[row] (row 0..31). 31 shfls. (verified)
__device__ __forceinline__ void reduce_accum(float v[16], float* sp,
                                             int l31, int lh) {
#pragma unroll
  for (int r = 0; r < 8; r++) {
    float a = v[r]     + __shfl_xor(v[r],     1, 32);
    float b = v[r + 8] + __shfl_xor(v[r + 8], 1, 32);
    v[r] = (l31 & 1) ? b : a;
  }
#pragma unroll
  for (int r = 0; r < 4; r++) {
    float a = v[r]     + __shfl_xor(v[r],     2, 32);
    float b = v[r + 4] + __shfl_xor(v[r + 4], 2, 32);
    v[r] = (l31 & 2) ? b : a;
  }
#pragma unroll
  for (int r = 0; r < 2; r++) {
    float a = v[r]     + __shfl_xor(v[r],     4, 32);
    float b = v[r + 2] + __shfl_xor(v[r + 2], 4, 32);
    v[r] = (l31 & 4) ? b : a;
  }
  {
    float a = v[0] + __shfl_xor(v[0], 8, 32);
    float b = v[1] + __shfl_xor(v[1], 8, 32);
    v[0] = (l31 & 8) ? b : a;
  }
  v[0] += __shfl_xor(v[0], 16, 32);
  if (l31 < 16) {
    const int i = ((l31 & 1) << 3) | ((l31 & 2) << 1) | ((l31 & 4) >> 1) |
                  ((l31 & 8) >> 3);
    const int row = (i & 3) + 8 * (i >> 2) + 4 * lh;
    atomicAdd(&sp[row], v[0]);
  }
}

__global__ __launch_bounds__(NT, 4)
void fused(const float* __restrict__ X0g, const float* __restrict__ X1g,
           const u16* __restrict__ Wf, float* __restrict__ outg) {
  __shared__ u16 lX0[BM][LDW];   // 16.9 KB
  __shared__ u16 lX1[BM][LDW];   // 16.9 KB
  __shared__ float sp0[BM], sp1[BM];

  const int t = threadIdx.x;
  const int row0 = blockIdx.x * BM;

  if (t < BM) sp0[t] = 0.f;
  else if (t < 2 * BM) sp1[t - BM] = 0.f;

  // ---- stage: fp32 global -> bf16 LDS (2048 float4/tensor, 4 iters; verified) ----
  {
    const float4* g0 = (const float4*)(X0g + (size_t)row0 * D256);
    const float4* g1 = (const float4*)(X1g + (size_t)row0 * D256);
    uint2* s0 = (uint2*)&lX0[0][0];   // row stride = 66 uint2
    uint2* s1 = (uint2*)&lX1[0][0];
#pragma unroll
    for (int i = 0; i < 4; i++) {
      const int e = i * NT + t;         // 64 float4 per row
      const int row = e >> 6;
      const int col = e & 63;
      float4 a = g0[e];
      float4 b = g1[e];
      uint2 pa, pb;
      pa.x = f2b2(a.x, a.y); pa.y = f2b2(a.z, a.w);
      pb.x = f2b2(b.x, b.y); pb.y = f2b2(b.z, b.w);
      s0[row * 66 + col] = pa;
      s1[row * 66 + col] = pb;
    }
  }
  __syncthreads();   // LDS tiles + sp zero-init visible

  const int ln  = t & 63;
  const int wv  = t >> 6;      // wave 0..7 = column panel
  const int l31 = ln & 31;
  const int lh  = ln >> 5;
  const int cb  = wv * 32;

  // fragment-ordered weight streams: 1KB contiguous per (mat, k)
  const u16* wA1 = Wf + 0 * 65536 + (wv * 16) * 512 + ln * 8;
  const u16* wA2 = Wf + 1 * 65536 + (wv * 16) * 512 + ln * 8;
  const u16* wW1 = Wf + 2 * 65536 + (wv * 16) * 512 + ln * 8;
  const u16* wW2 = Wf + 3 * 65536 + (wv * 16) * 512 + ln * 8;

  // ---- fused k-loop: gates + projections share the A-fragments ----
  f32x16 G0, G1, P0, P1;
#pragma unroll
  for (int i = 0; i < 16; i++) { G0[i] = 0.f; G1[i] = 0.f;
                                 P0[i] = 0.f; P1[i] = 0.f; }

#pragma unroll 4
  for (int k = 0; k < 16; k++) {
    bf16x8 af0 = *(const bf16x8*)(&lX0[l31][k * 16 + lh * 8]);
    bf16x8 af1 = *(const bf16x8*)(&lX1[l31][k * 16 + lh * 8]);
    bf16x8 wa1 = *(const bf16x8*)(wA1 + k * 512);
    bf16x8 wa2 = *(const bf16x8*)(wA2 + k * 512);
    bf16x8 ww1 = *(const bf16x8*)(wW1 + k * 512);
    bf16x8 ww2 = *(const bf16x8*)(wW2 + k * 512);
    G0 = __builtin_amdgcn_mfma_f32_32x32x16_bf16(af0, wa1, G0, 0, 0, 0);
    P0 = __builtin_amdgcn_mfma_f32_32x32x16_bf16(af0, ww1, P0, 0, 0, 0);
    G1 = __builtin_amdgcn_mfma_f32_32x32x16_bf16(af1, wa2, G1, 0, 0, 0);
    P1 = __builtin_amdgcn_mfma_f32_32x32x16_bf16(af1, ww2, P1, 0, 0, 0);
  }

  // ---- gate elementwise + cross-lane reduce (verified r0 code) ----
  {
    float v[16];
#pragma unroll
    for (int r = 0; r < 16; r++) {   // gate0: Z0 = X0@A1^T, other = X1
      const int row = (r & 3) + 8 * (r >> 2) + 4 * lh;
      v[r] = G0[r] * b2f(lX1[row][cb + l31]);
    }
    reduce_accum(v, sp0, l31, lh);
#pragma unroll
    for (int r = 0; r < 16; r++) {   // gate1: Z1 = X1@A2^T, other = X0
      const int row = (r & 3) + 8 * (r >> 2) + 4 * lh;
      v[r] = G1[r] * b2f(lX0[row][cb + l31]);
    }
    reduce_accum(v, sp1, l31, lh);
  }
  __syncthreads();   // sp complete

  // ---- epilogue: inline sigmoid from sp, gate-scale P, store, end ----
  {
    float* opb = outg + (size_t)row0 * 256 + cb;
#pragma unroll
    for (int q = 0; q < 4; q++) {
#pragma unroll
      for (int j = 0; j < 4; j++) {
        const int r = q * 4 + j;
        const int row = j + 8 * q + 4 * lh;
        const float s0 = 1.f + 1.f / (1.f + __expf(-sp0[row]));
        const float s1 = 1.f + 1.f / (1.f + __expf(-sp1[row]));
        __builtin_nontemporal_store(s0 * P0[r] + s1 * P1[r],
                                    &opb[row * 256 + l31]);
      }
    }
  }
}

extern "C" void kernel_launch(void* const* d_in, const int* in_sizes, int n_in,
                              void* d_out, int out_size, void* d_ws, size_t ws_size,
                              hipStream_t stream) {
  const float* i0 = (const float*)d_in[0];
  const float* i1 = (const float*)d_in[1];
  const float* W1 = (const float*)d_in[2];
  const float* W2 = (const float*)d_in[3];
  const float* a1 = (const float*)d_in[4];
  const float* a2 = (const float*)d_in[5];
  u16* Wf = (u16*)d_ws;   // 4 x 256x256 bf16 = 512 KB, fragment-ordered

  build_wfrag<<<dim3(32, 4), 256, 0, stream>>>(a1, a2, W1, W2, Wf);
  fused<<<NBLK, NT, 0, stream>>>(i0, i1, Wf, (float*)d_out);
}